// Round 3
// baseline (1680.248 us; speedup 1.0000x reference)
//
#include <hip/hip_runtime.h>

#define D 256

typedef __attribute__((ext_vector_type(8))) short short8;
typedef __attribute__((ext_vector_type(4))) float f32x4;

__device__ __forceinline__ ushort f2b(float f) {
    unsigned u = __float_as_uint(f);
    u += 0x7fffu + ((u >> 16) & 1u);   // round-to-nearest-even
    return (ushort)(u >> 16);
}
__device__ __forceinline__ float b2f(ushort h) {
    return __uint_as_float(((unsigned)h) << 16);
}

// ---------------- CSR build (blockIdx.y = hop) ----------------

__global__ void zero_int_kernel(int* __restrict__ p, int n) {
    int stride = gridDim.x * blockDim.x;
    for (int i = blockIdx.x * blockDim.x + threadIdx.x; i < n; i += stride) p[i] = 0;
}

__global__ void hist3_kernel(const int* __restrict__ rows, int* __restrict__ cnt, int e, int n) {
    int h = blockIdx.y;
    const int* r = rows + (size_t)h * e;
    int* c = cnt + (size_t)h * n;
    int stride = gridDim.x * blockDim.x;
    for (int i = blockIdx.x * blockDim.x + threadIdx.x; i < e; i += stride)
        atomicAdd(&c[r[i]], 1);
}

__global__ void scan_a3_kernel(const int* __restrict__ cnt, int* __restrict__ bsums, int n) {
    __shared__ int s[256];
    int h = blockIdx.y;
    int t = threadIdx.x;
    int i = blockIdx.x * 256 + t;
    s[t] = (i < n) ? cnt[(size_t)h * n + i] : 0;
    __syncthreads();
    for (int off = 128; off > 0; off >>= 1) {
        if (t < off) s[t] += s[t + off];
        __syncthreads();
    }
    if (t == 0) bsums[h * 512 + blockIdx.x] = s[0];
}

__global__ void scan_b3_kernel(const int* __restrict__ bsums, int* __restrict__ bbase, int nb) {
    __shared__ int s[512];
    int h = blockIdx.y;
    int t = threadIdx.x;
    int v = (t < nb) ? bsums[h * 512 + t] : 0;
    s[t] = v;
    __syncthreads();
    for (int off = 1; off < 512; off <<= 1) {
        int x = (t >= off) ? s[t - off] : 0;
        __syncthreads();
        s[t] += x;
        __syncthreads();
    }
    bbase[h * 512 + t] = s[t] - v;   // exclusive base per block
}

__global__ void scan_c3_kernel(const int* __restrict__ cnt, const int* __restrict__ bbase,
                               int* __restrict__ row_ptr, int n, int e) {
    __shared__ int s[256];
    int h = blockIdx.y;
    int t = threadIdx.x;
    int i = blockIdx.x * 256 + t;
    int v = (i < n) ? cnt[(size_t)h * n + i] : 0;
    s[t] = v;
    __syncthreads();
    for (int off = 1; off < 256; off <<= 1) {
        int x = (t >= off) ? s[t - off] : 0;
        __syncthreads();
        s[t] += x;
        __syncthreads();
    }
    int* rp = row_ptr + (size_t)h * (n + 1);
    if (i < n) rp[i] = bbase[h * 512 + blockIdx.x] + s[t] - v;
    if (i == 0) rp[n] = e;
}

__global__ void scatter3_kernel(const int* __restrict__ rows, const int* __restrict__ cols,
                                const float* __restrict__ vals, const int* __restrict__ row_ptr,
                                int* __restrict__ cur, int2* __restrict__ edges, int e, int n) {
    int h = blockIdx.y;
    const int*   rr = rows + (size_t)h * e;
    const int*   cc = cols + (size_t)h * e;
    const float* vv = vals + (size_t)h * e;
    const int*   rp = row_ptr + (size_t)h * (n + 1);
    int*  cu = cur + (size_t)h * n;
    int2* eg = edges + (size_t)h * e;
    int stride = gridDim.x * blockDim.x;
    for (int i = blockIdx.x * blockDim.x + threadIdx.x; i < e; i += stride) {
        int r = rr[i];
        int p = rp[r] + atomicAdd(&cu[r], 1);
        eg[p] = make_int2(cc[i], __float_as_int(vv[i]));
    }
}

// ---------------- conversions ----------------
// Xb[i] = bf16(X[i]), 8 elems/thread
__global__ void xconv_kernel(const float* __restrict__ X, ushort* __restrict__ Xb, int total8) {
    int i = blockIdx.x * 256 + threadIdx.x;
    if (i >= total8) return;
    const float4 a = *(const float4*)(X + (size_t)i * 8);
    const float4 b = *(const float4*)(X + (size_t)i * 8 + 4);
    ushort o8[8] = {f2b(a.x), f2b(a.y), f2b(a.z), f2b(a.w),
                    f2b(b.x), f2b(b.y), f2b(b.z), f2b(b.w)};
    *(short8*)(Xb + (size_t)i * 8) = *(const short8*)o8;
}

// WT[h][c][k] = bf16(W[h][k][c])
__global__ void wconv_kernel(const float* __restrict__ W, ushort* __restrict__ WT, int total) {
    int idx = blockIdx.x * 256 + threadIdx.x;
    if (idx >= total) return;
    int h = idx >> 16;
    int c = (idx >> 8) & 255, k = idx & 255;
    WT[(h << 16) + c * 256 + k] = f2b(W[(h << 16) + k * 256 + c]);
}

// ---------------- SpMM: Yh = A_h * Xb (one hop), atomic-free, 4-deep gather pipeline ----------------
__global__ __launch_bounds__(256) void spmmX_kernel(const int* __restrict__ rp,
                                                    const int2* __restrict__ eg,
                                                    const ushort* __restrict__ Xb,
                                                    ushort* __restrict__ Yh, int n) {
    int w = threadIdx.x >> 6, lane = threadIdx.x & 63;
    int r = blockIdx.x * 4 + w;
    if (r >= n) return;
    int half = lane >> 5, l5 = lane & 31;
    int doff = l5 * 8;
    int e0 = rp[r], e1 = rp[r + 1];
    float acc[8] = {};
    int m0 = e0 + half, m1 = e0 + 2 + half;
    int2 ev0 = (m0 < e1) ? eg[m0] : make_int2(0, 0);
    int2 ev1 = (m1 < e1) ? eg[m1] : make_int2(0, 0);
    for (int ee = e0; ee < e1; ee += 4) {
        int2 c0 = ev0, c1 = ev1;
        int n0 = ee + 4 + half, n1 = ee + 6 + half;
        ev0 = (n0 < e1) ? eg[n0] : make_int2(0, 0);
        ev1 = (n1 < e1) ? eg[n1] : make_int2(0, 0);
        short8 v0 = *(const short8*)(Xb + (size_t)c0.x * 256 + doff);
        short8 v1 = *(const short8*)(Xb + (size_t)c1.x * 256 + doff);
        float val0 = __int_as_float(c0.y);
        float val1 = __int_as_float(c1.y);
        #pragma unroll
        for (int i = 0; i < 8; ++i)
            acc[i] = fmaf(val0, b2f((ushort)v0[i]), acc[i]);
        #pragma unroll
        for (int i = 0; i < 8; ++i)
            acc[i] = fmaf(val1, b2f((ushort)v1[i]), acc[i]);
    }
    // combine the two half-wave partial sums
    #pragma unroll
    for (int i = 0; i < 8; ++i)
        acc[i] += __shfl_xor(acc[i], 32);
    if (half == 0) {
        ushort o8[8];
        #pragma unroll
        for (int i = 0; i < 8; ++i) o8[i] = f2b(acc[i]);
        *(short8*)(Yh + (size_t)r * 256 + doff) = *(const short8*)o8;
    }
}

// ---------------- GEMM: out = [relu](Σ_h Y_h @ W_h) [+ prev out] ----------------
#define APAD 40   // padded LDS row (bf16 elems): 80B rows keep 16B alignment

__global__ __launch_bounds__(256) void gemmY_kernel(const ushort* __restrict__ Y,
                                                    const ushort* __restrict__ WT,
                                                    float* __restrict__ out, int M,
                                                    int nh, int mode) {
    __shared__ ushort As[64 * APAD];
    __shared__ ushort Bs[64 * APAD];
    int tid = threadIdx.x;
    int r0 = blockIdx.x * 64, c0 = blockIdx.y * 64;
    int w = tid >> 6, lane = tid & 63;
    int wr = w >> 1, wc = w & 1;
    int lo = lane & 15, hi = lane >> 4;
    f32x4 acc[2][2] = {};
    int srow = tid >> 2;           // 0..63
    int skoff = (tid & 3) * 8;     // 0,8,16,24
    int arow = r0 + srow; if (arow > M - 1) arow = M - 1;
    for (int h = 0; h < nh; ++h) {
        const ushort* ap = Y + ((size_t)h * M + arow) * 256 + skoff;
        const ushort* bp = WT + ((size_t)h << 16) + (size_t)(c0 + srow) * 256 + skoff;
        for (int kk = 0; kk < 256; kk += 32) {
            short8 av = *(const short8*)(ap + kk);
            short8 bv = *(const short8*)(bp + kk);
            __syncthreads();
            *(short8*)&As[srow * APAD + skoff] = av;
            *(short8*)&Bs[srow * APAD + skoff] = bv;
            __syncthreads();
            short8 a0 = *(const short8*)&As[(wr * 32 +      lo) * APAD + hi * 8];
            short8 a1 = *(const short8*)&As[(wr * 32 + 16 + lo) * APAD + hi * 8];
            short8 b0 = *(const short8*)&Bs[(wc * 32 +      lo) * APAD + hi * 8];
            short8 b1 = *(const short8*)&Bs[(wc * 32 + 16 + lo) * APAD + hi * 8];
            acc[0][0] = __builtin_amdgcn_mfma_f32_16x16x32_bf16(a0, b0, acc[0][0], 0, 0, 0);
            acc[0][1] = __builtin_amdgcn_mfma_f32_16x16x32_bf16(a0, b1, acc[0][1], 0, 0, 0);
            acc[1][0] = __builtin_amdgcn_mfma_f32_16x16x32_bf16(a1, b0, acc[1][0], 0, 0, 0);
            acc[1][1] = __builtin_amdgcn_mfma_f32_16x16x32_bf16(a1, b1, acc[1][1], 0, 0, 0);
        }
    }
    // C/D layout (HW-verified): col = lane&15, row = (lane>>4)*4 + reg
    for (int mi = 0; mi < 2; ++mi)
        for (int ni = 0; ni < 2; ++ni)
            for (int i = 0; i < 4; ++i) {
                int row = r0 + wr * 32 + mi * 16 + hi * 4 + i;
                int col = c0 + wc * 32 + ni * 16 + lo;
                if (row < M) {
                    float v = acc[mi][ni][i];
                    float* op = &out[(size_t)row * 256 + col];
                    if (mode & 1) v += *op;
                    if (mode & 2) v = fmaxf(v, 0.f);
                    *op = v;
                }
            }
}

extern "C" void kernel_launch(void* const* d_in, const int* in_sizes, int n_in,
                              void* d_out, int out_size, void* d_ws, size_t ws_size,
                              hipStream_t stream) {
    const float* X    = (const float*)d_in[0];
    const float* W    = (const float*)d_in[1];
    const float* vals = (const float*)d_in[2];
    const int*   rows = (const int*)d_in[3];
    const int*   cols = (const int*)d_in[4];
    int n    = in_sizes[0] / D;         // 100000
    int hops = in_sizes[1] / (D * D);   // 3
    int e    = in_sizes[2] / hops;      // 3200000
    int nblk = (n + 255) / 256;         // 391 (<= 512 for scan_b)

    float* out = (float*)d_out;

    auto padded = [](size_t b) { return (b + 255) & ~(size_t)255; };
    size_t sz_WT   = padded((size_t)hops * D * D * 2);
    size_t sz_Xb   = padded((size_t)n * D * 2);
    size_t sz_Yall = padded((size_t)hops * n * D * 2);
    size_t sz_Y1   = padded((size_t)n * D * 2);
    size_t sz_cnt  = padded((size_t)hops * n * 4);
    size_t sz_bs   = padded((size_t)hops * 512 * 4);
    size_t sz_rp   = padded((size_t)hops * (n + 1) * 4);
    size_t sz_eg   = padded((size_t)hops * e * 8);
    size_t common  = sz_WT + sz_Xb + sz_cnt + sz_bs + sz_bs + sz_rp + sz_eg;
    bool bigY = (ws_size >= common + sz_Yall);

    char* wsb = (char*)d_ws;
    size_t off = 0;
    auto alloc = [&](size_t bytes) -> void* { void* p = wsb + off; off += padded(bytes); return p; };

    ushort* WT      = (ushort*)alloc((size_t)hops * D * D * 2);
    ushort* Xb      = (ushort*)alloc((size_t)n * D * 2);
    int*    cnt     = (int*)   alloc((size_t)hops * n * 4);
    int*    bsums   = (int*)   alloc((size_t)hops * 512 * 4);
    int*    bbase   = (int*)   alloc((size_t)hops * 512 * 4);
    int*    row_ptr = (int*)   alloc((size_t)hops * (n + 1) * 4);
    int2*   edges   = (int2*)  alloc((size_t)hops * e * 8);
    ushort* Y       = (ushort*)alloc(bigY ? (size_t)hops * n * D * 2 : (size_t)n * D * 2);

    // conversions first (independent of CSR)
    xconv_kernel<<<(n * D / 8 + 255) / 256, 256, 0, stream>>>(X, Xb, n * D / 8);
    wconv_kernel<<<(hops * D * D + 255) / 256, 256, 0, stream>>>(W, WT, hops * D * D);

    // CSR build, all hops via blockIdx.y
    zero_int_kernel<<<1024, 256, 0, stream>>>(cnt, hops * n);
    hist3_kernel<<<dim3(2048, hops), 256, 0, stream>>>(rows, cnt, e, n);
    scan_a3_kernel<<<dim3(nblk, hops), 256, 0, stream>>>(cnt, bsums, n);
    scan_b3_kernel<<<dim3(1, hops), 512, 0, stream>>>(bsums, bbase, nblk);
    scan_c3_kernel<<<dim3(nblk, hops), 256, 0, stream>>>(cnt, bbase, row_ptr, n, e);
    zero_int_kernel<<<1024, 256, 0, stream>>>(cnt, hops * n);
    scatter3_kernel<<<dim3(2048, hops), 256, 0, stream>>>(rows, cols, vals, row_ptr, cnt, edges, e, n);

    if (bigY) {
        // 3x SpMM (shared 51MB L3-resident gather target), then one K=768 GEMM
        for (int h = 0; h < hops; ++h)
            spmmX_kernel<<<(n + 3) / 4, 256, 0, stream>>>(row_ptr + (size_t)h * (n + 1),
                                                          edges + (size_t)h * e, Xb,
                                                          Y + (size_t)h * n * D, n);
        gemmY_kernel<<<dim3((n + 63) / 64, D / 64), 256, 0, stream>>>(Y, WT, out, n, hops, 2);
    } else {
        // per-hop Y buffer, accumulate into f32 out
        for (int h = 0; h < hops; ++h) {
            spmmX_kernel<<<(n + 3) / 4, 256, 0, stream>>>(row_ptr + (size_t)h * (n + 1),
                                                          edges + (size_t)h * e, Xb, Y, n);
            int mode = (h > 0 ? 1 : 0) | (h == hops - 1 ? 2 : 0);
            gemmY_kernel<<<dim3((n + 63) / 64, D / 64), 256, 0, stream>>>(Y, WT + (size_t)h * D * D,
                                                                          out, n, 1, mode);
        }
    }
}